// Round 4
// baseline (1181.118 us; speedup 1.0000x reference)
//
#include <hip/hip_runtime.h>
#include <math.h>

#define F 32
#define K 16
#define EPSN 1e-8f

typedef float f32x4 __attribute__((ext_vector_type(4)));

// ws layout (floats): per-degree blocks of normalized W rows.
// deg d block: rows 0..15 = Wf_norm, rows 16..16+16*d-1 = Wn_norm flat (k*d+j).
// offsets: d1 @ 0 (32 rows), d2 @ 1024 (48), d3 @ 2560 (64), d4 @ 4608 (80).

__global__ __launch_bounds__(128)
void prep_w(const float* __restrict__ Wf1, const float* __restrict__ Wn1,
            const float* __restrict__ Wf2, const float* __restrict__ Wn2,
            const float* __restrict__ Wf3, const float* __restrict__ Wn3,
            const float* __restrict__ Wf4, const float* __restrict__ Wn4,
            float* __restrict__ ws)
{
    const int deg = blockIdx.x + 1;
    const int NW = K * (1 + deg);
    const int tid = threadIdx.x;
    if (tid >= NW) return;

    const float* Wf; const float* Wn; int off;
    switch (deg) {
        case 1: Wf = Wf1; Wn = Wn1; off = 0;    break;
        case 2: Wf = Wf2; Wn = Wn2; off = 1024; break;
        case 3: Wf = Wf3; Wn = Wn3; off = 2560; break;
        default: Wf = Wf4; Wn = Wn4; off = 4608; break;
    }
    const float* src = (tid < K) ? (Wf + tid * F) : (Wn + (tid - K) * F);
    float ss = 0.f;
    #pragma unroll
    for (int f = 0; f < F; ++f) { float v = src[f]; ss += v * v; }
    const float sc = 1.f / (sqrtf(ss) + EPSN);
    #pragma unroll
    for (int f = 0; f < F; ++f) ws[off + tid * F + f] = src[f] * sc;
}

// Accumulate 16 dot products of (normalized, scaled) row xr against W rows
// wbase[k*kstride + f] (wbase uniform -> scalar loads).
__device__ __forceinline__ void row_accum(const float* __restrict__ xr,
                                          const float* __restrict__ wbase,
                                          int kstride, float scale, float* acc)
{
    float r[F];
    #pragma unroll
    for (int q = 0; q < F / 4; ++q) {
        const f32x4 v = ((const f32x4*)xr)[q];
        r[4 * q + 0] = v.x; r[4 * q + 1] = v.y; r[4 * q + 2] = v.z; r[4 * q + 3] = v.w;
    }
    float ss = 0.f;
    #pragma unroll
    for (int f = 0; f < F; ++f) ss += r[f] * r[f];
    const float sc = scale / (sqrtf(ss) + EPSN);
    #pragma unroll
    for (int f = 0; f < F; ++f) r[f] *= sc;
    #pragma unroll
    for (int k = 0; k < K; ++k) {
        float s = 0.f;
        #pragma unroll
        for (int f = 0; f < F; ++f) s += wbase[k * kstride + f] * r[f];
        acc[k] += s;
    }
}

template<int DEG>
__device__ __forceinline__ void process_deg(const float* __restrict__ x,
                                            const int*   __restrict__ sel,
                                            const int*   __restrict__ nei,
                                            const float* __restrict__ wdeg,
                                            float* __restrict__ out,
                                            int nd, int i0)
{
    const int i = i0 + threadIdx.x;
    if (i >= nd) return;

    const int node = sel[i];
    int nn[DEG];
    #pragma unroll
    for (int j = 0; j < DEG; ++j) nn[j] = nei[i * DEG + j];

    float acc[K];
    #pragma unroll
    for (int k = 0; k < K; ++k) acc[k] = 0.f;

    // focal: rows 0..15, stride F
    row_accum(x + (size_t)node * F, wdeg, F, 1.f, acc);
    // neighbor slot j: row (K + k*DEG + j) -> base wdeg + (K + j)*F, stride DEG*F
    #pragma unroll
    for (int j = 0; j < DEG; ++j)
        row_accum(x + (size_t)nn[j] * F, wdeg + (K + j) * F, DEG * F,
                  1.f / (float)DEG, acc);

    // full 64-float output row: zeros except this degree's 16-block (nontemporal)
    f32x4* o = (f32x4*)(out + (size_t)node * (4 * K));
    const f32x4 z = {0.f, 0.f, 0.f, 0.f};
    #pragma unroll
    for (int b = 0; b < 4; ++b) {
        if (b == DEG - 1) {
            f32x4 v0 = {acc[0],  acc[1],  acc[2],  acc[3]};
            f32x4 v1 = {acc[4],  acc[5],  acc[6],  acc[7]};
            f32x4 v2 = {acc[8],  acc[9],  acc[10], acc[11]};
            f32x4 v3 = {acc[12], acc[13], acc[14], acc[15]};
            __builtin_nontemporal_store(v0, &o[b*4+0]);
            __builtin_nontemporal_store(v1, &o[b*4+1]);
            __builtin_nontemporal_store(v2, &o[b*4+2]);
            __builtin_nontemporal_store(v3, &o[b*4+3]);
        } else {
            __builtin_nontemporal_store(z, &o[b*4+0]);
            __builtin_nontemporal_store(z, &o[b*4+1]);
            __builtin_nontemporal_store(z, &o[b*4+2]);
            __builtin_nontemporal_store(z, &o[b*4+3]);
        }
    }
}

struct Args {
    const float* x;
    const int*   sel[4];
    const int*   nei[4];
    int nd[4];
    int bcum[4];
};

__global__ __launch_bounds__(256, 6)
void fused_kernel(Args a, const float* __restrict__ ws, float* __restrict__ out)
{
    const int bid = blockIdx.x;
    if (bid < a.bcum[0]) {
        process_deg<1>(a.x, a.sel[0], a.nei[0], ws + 0,    out, a.nd[0], bid * 256);
    } else if (bid < a.bcum[1]) {
        process_deg<2>(a.x, a.sel[1], a.nei[1], ws + 1024, out, a.nd[1], (bid - a.bcum[0]) * 256);
    } else if (bid < a.bcum[2]) {
        process_deg<3>(a.x, a.sel[2], a.nei[2], ws + 2560, out, a.nd[2], (bid - a.bcum[1]) * 256);
    } else {
        process_deg<4>(a.x, a.sel[3], a.nei[3], ws + 4608, out, a.nd[3], (bid - a.bcum[2]) * 256);
    }
}

extern "C" void kernel_launch(void* const* d_in, const int* in_sizes, int n_in,
                              void* d_out, int out_size, void* d_ws, size_t ws_size,
                              hipStream_t stream)
{
    Args a;
    a.x = (const float*)d_in[0];
    const float* Wf[4]; const float* Wn[4];
    for (int d = 0; d < 4; ++d) {
        a.sel[d] = (const int*)  d_in[1 + 4 * d];
        a.nei[d] = (const int*)  d_in[2 + 4 * d];
        Wf[d]    = (const float*)d_in[3 + 4 * d];
        Wn[d]    = (const float*)d_in[4 + 4 * d];
        a.nd[d]  = in_sizes[1 + 4 * d];
    }
    int cum = 0;
    for (int d = 0; d < 4; ++d) {
        cum += (a.nd[d] + 255) / 256;
        a.bcum[d] = cum;
    }
    float* ws = (float*)d_ws;
    float* out = (float*)d_out;

    prep_w<<<4, 128, 0, stream>>>(Wf[0], Wn[0], Wf[1], Wn[1],
                                  Wf[2], Wn[2], Wf[3], Wn[3], ws);
    fused_kernel<<<cum, 256, 0, stream>>>(a, ws, out);
}

// Round 5
// 873.415 us; speedup vs baseline: 1.3523x; 1.3523x over previous
//
#include <hip/hip_runtime.h>
#include <math.h>

#define F 32
#define K 16
#define EPSN 1e-8f

typedef float f32x4 __attribute__((ext_vector_type(4)));

// ws layout (floats): per-degree blocks of normalized W rows.
// deg d block: rows 0..15 = Wf_norm, rows 16..16+16*d-1 = Wn_norm flat (k*d+j).
// offsets: d1 @ 0 (32 rows), d2 @ 1024 (48), d3 @ 2560 (64), d4 @ 4608 (80).

__global__ __launch_bounds__(128)
void prep_w(const float* __restrict__ Wf1, const float* __restrict__ Wn1,
            const float* __restrict__ Wf2, const float* __restrict__ Wn2,
            const float* __restrict__ Wf3, const float* __restrict__ Wn3,
            const float* __restrict__ Wf4, const float* __restrict__ Wn4,
            float* __restrict__ ws)
{
    const int deg = blockIdx.x + 1;
    const int NW = K * (1 + deg);
    const int tid = threadIdx.x;
    if (tid >= NW) return;

    const float* Wf; const float* Wn; int off;
    switch (deg) {
        case 1: Wf = Wf1; Wn = Wn1; off = 0;    break;
        case 2: Wf = Wf2; Wn = Wn2; off = 1024; break;
        case 3: Wf = Wf3; Wn = Wn3; off = 2560; break;
        default: Wf = Wf4; Wn = Wn4; off = 4608; break;
    }
    const float* src = (tid < K) ? (Wf + tid * F) : (Wn + (tid - K) * F);
    float ss = 0.f;
    #pragma unroll
    for (int f = 0; f < F; ++f) { float v = src[f]; ss += v * v; }
    const float sc = 1.f / (sqrtf(ss) + EPSN);
    #pragma unroll
    for (int f = 0; f < F; ++f) ws[off + tid * F + f] = src[f] * sc;
}

// Accumulate 16 dot products of (normalized, scaled) row xr against W rows
// wbase[k*kstride + f] (wbase uniform -> scalar loads, v_fmac v,s,v).
__device__ __forceinline__ void row_accum(const float* __restrict__ xr,
                                          const float* __restrict__ wbase,
                                          int kstride, float scale, float* acc)
{
    float r[F];
    #pragma unroll
    for (int q = 0; q < F / 4; ++q) {
        const f32x4 v = ((const f32x4*)xr)[q];
        r[4 * q + 0] = v.x; r[4 * q + 1] = v.y; r[4 * q + 2] = v.z; r[4 * q + 3] = v.w;
    }
    float ss = 0.f;
    #pragma unroll
    for (int f = 0; f < F; ++f) ss += r[f] * r[f];
    const float sc = scale / (sqrtf(ss) + EPSN);
    #pragma unroll
    for (int f = 0; f < F; ++f) r[f] *= sc;
    #pragma unroll
    for (int k = 0; k < K; ++k) {
        float s = 0.f;
        #pragma unroll
        for (int f = 0; f < F; ++f) s += wbase[k * kstride + f] * r[f];
        acc[k] += s;
    }
}

template<int DEG>
__device__ __forceinline__ void process_deg(const float* __restrict__ x,
                                            const int*   __restrict__ sel,
                                            const int*   __restrict__ nei,
                                            const float* __restrict__ wdeg,
                                            float* __restrict__ out,
                                            int nd, int i0)
{
    const int i = i0 + threadIdx.x;
    if (i >= nd) return;

    const int node = sel[i];
    int nn[DEG];
    #pragma unroll
    for (int j = 0; j < DEG; ++j) nn[j] = nei[i * DEG + j];

    float acc[K];
    #pragma unroll
    for (int k = 0; k < K; ++k) acc[k] = 0.f;

    // focal: rows 0..15, stride F
    row_accum(x + (size_t)node * F, wdeg, F, 1.f, acc);
    // neighbor slot j: row (K + k*DEG + j) -> base wdeg + (K + j)*F, stride DEG*F
    #pragma unroll
    for (int j = 0; j < DEG; ++j)
        row_accum(x + (size_t)nn[j] * F, wdeg + (K + j) * F, DEG * F,
                  1.f / (float)DEG, acc);

    // full 64-float output row: zeros except this degree's 16-block.
    // PLAIN stores: rows are permutation-scattered; L2 write-back coalesces
    // each thread's 4 full lines. (NT stores here caused 6x write amplification.)
    f32x4* o = (f32x4*)(out + (size_t)node * (4 * K));
    const f32x4 z = {0.f, 0.f, 0.f, 0.f};
    #pragma unroll
    for (int b = 0; b < 4; ++b) {
        if (b == DEG - 1) {
            o[b*4+0] = f32x4{acc[0],  acc[1],  acc[2],  acc[3]};
            o[b*4+1] = f32x4{acc[4],  acc[5],  acc[6],  acc[7]};
            o[b*4+2] = f32x4{acc[8],  acc[9],  acc[10], acc[11]};
            o[b*4+3] = f32x4{acc[12], acc[13], acc[14], acc[15]};
        } else {
            o[b*4+0] = z; o[b*4+1] = z; o[b*4+2] = z; o[b*4+3] = z;
        }
    }
}

struct Args {
    const float* x;
    const int*   sel[4];
    const int*   nei[4];
    int nd[4];
    int bcum[4];
};

__global__ __launch_bounds__(256, 6)
void fused_kernel(Args a, const float* __restrict__ ws, float* __restrict__ out)
{
    const int bid = blockIdx.x;
    if (bid < a.bcum[0]) {
        process_deg<1>(a.x, a.sel[0], a.nei[0], ws + 0,    out, a.nd[0], bid * 256);
    } else if (bid < a.bcum[1]) {
        process_deg<2>(a.x, a.sel[1], a.nei[1], ws + 1024, out, a.nd[1], (bid - a.bcum[0]) * 256);
    } else if (bid < a.bcum[2]) {
        process_deg<3>(a.x, a.sel[2], a.nei[2], ws + 2560, out, a.nd[2], (bid - a.bcum[1]) * 256);
    } else {
        process_deg<4>(a.x, a.sel[3], a.nei[3], ws + 4608, out, a.nd[3], (bid - a.bcum[2]) * 256);
    }
}

extern "C" void kernel_launch(void* const* d_in, const int* in_sizes, int n_in,
                              void* d_out, int out_size, void* d_ws, size_t ws_size,
                              hipStream_t stream)
{
    Args a;
    a.x = (const float*)d_in[0];
    const float* Wf[4]; const float* Wn[4];
    for (int d = 0; d < 4; ++d) {
        a.sel[d] = (const int*)  d_in[1 + 4 * d];
        a.nei[d] = (const int*)  d_in[2 + 4 * d];
        Wf[d]    = (const float*)d_in[3 + 4 * d];
        Wn[d]    = (const float*)d_in[4 + 4 * d];
        a.nd[d]  = in_sizes[1 + 4 * d];
    }
    int cum = 0;
    for (int d = 0; d < 4; ++d) {
        cum += (a.nd[d] + 255) / 256;
        a.bcum[d] = cum;
    }
    float* ws = (float*)d_ws;
    float* out = (float*)d_out;

    prep_w<<<4, 128, 0, stream>>>(Wf[0], Wn[0], Wf[1], Wn[1],
                                  Wf[2], Wn[2], Wf[3], Wn[3], ws);
    fused_kernel<<<cum, 256, 0, stream>>>(a, ws, out);
}

// Round 6
// 596.659 us; speedup vs baseline: 1.9796x; 1.4638x over previous
//
#include <hip/hip_runtime.h>
#include <math.h>

#define F 32
#define K 16
#define EPSN 1e-8f

typedef float f32x4 __attribute__((ext_vector_type(4)));

// ws layout (float units):
//   [0, 7168): normalized W rows, per-degree blocks:
//     d1 @ 0 (32 rows), d2 @ 1024 (48), d3 @ 2560 (64), d4 @ 4608 (80)
//   [7168, 7168+N): inv map (int): ((deg-1)<<28) | global_slot
//   [7168+N, 7168+N+16N): scored staging, 16 floats per global slot (dense)
#define WROWS_FLOATS 7168

__global__ __launch_bounds__(128)
void prep_w(const float* __restrict__ Wf1, const float* __restrict__ Wn1,
            const float* __restrict__ Wf2, const float* __restrict__ Wn2,
            const float* __restrict__ Wf3, const float* __restrict__ Wn3,
            const float* __restrict__ Wf4, const float* __restrict__ Wn4,
            float* __restrict__ ws)
{
    const int deg = blockIdx.x + 1;
    const int NW = K * (1 + deg);
    const int tid = threadIdx.x;
    if (tid >= NW) return;

    const float* Wf; const float* Wn; int off;
    switch (deg) {
        case 1: Wf = Wf1; Wn = Wn1; off = 0;    break;
        case 2: Wf = Wf2; Wn = Wn2; off = 1024; break;
        case 3: Wf = Wf3; Wn = Wn3; off = 2560; break;
        default: Wf = Wf4; Wn = Wn4; off = 4608; break;
    }
    const float* src = (tid < K) ? (Wf + tid * F) : (Wn + (tid - K) * F);
    float ss = 0.f;
    #pragma unroll
    for (int f = 0; f < F; ++f) { float v = src[f]; ss += v * v; }
    const float sc = 1.f / (sqrtf(ss) + EPSN);
    #pragma unroll
    for (int f = 0; f < F; ++f) ws[off + tid * F + f] = src[f] * sc;
}

// 16 dots of normalized/scaled row xr vs W rows wbase[k*kstride+f] (uniform -> scalar loads)
__device__ __forceinline__ void row_accum(const float* __restrict__ xr,
                                          const float* __restrict__ wbase,
                                          int kstride, float scale, float* acc)
{
    float r[F];
    #pragma unroll
    for (int q = 0; q < F / 4; ++q) {
        const f32x4 v = ((const f32x4*)xr)[q];
        r[4 * q + 0] = v.x; r[4 * q + 1] = v.y; r[4 * q + 2] = v.z; r[4 * q + 3] = v.w;
    }
    float ss = 0.f;
    #pragma unroll
    for (int f = 0; f < F; ++f) ss += r[f] * r[f];
    const float sc = scale / (sqrtf(ss) + EPSN);
    #pragma unroll
    for (int f = 0; f < F; ++f) r[f] *= sc;
    #pragma unroll
    for (int k = 0; k < K; ++k) {
        float s = 0.f;
        #pragma unroll
        for (int f = 0; f < F; ++f) s += wbase[k * kstride + f] * r[f];
        acc[k] += s;
    }
}

template<int DEG>
__device__ __forceinline__ void compute_acc(const float* __restrict__ x,
                                            const int*   __restrict__ sel,
                                            const int*   __restrict__ nei,
                                            const float* __restrict__ wdeg,
                                            int i, int* node_out, float* acc)
{
    const int node = sel[i];
    *node_out = node;
    int nn[DEG];
    #pragma unroll
    for (int j = 0; j < DEG; ++j) nn[j] = nei[i * DEG + j];

    #pragma unroll
    for (int k = 0; k < K; ++k) acc[k] = 0.f;

    row_accum(x + (size_t)node * F, wdeg, F, 1.f, acc);
    #pragma unroll
    for (int j = 0; j < DEG; ++j)
        row_accum(x + (size_t)nn[j] * F, wdeg + (K + j) * F, DEG * F,
                  1.f / (float)DEG, acc);
}

struct Args {
    const float* x;
    const int*   sel[4];
    const int*   nei[4];
    int nd[4];
    int bcum[4];
    int sbase[4];   // global slot base per degree
};

// ---------------- two-pass path ----------------

template<int DEG>
__device__ __forceinline__ void pass1_deg(const Args& a, const float* __restrict__ ws,
                                          int* __restrict__ inv, float* __restrict__ scored,
                                          int d0, int i0)
{
    const int i = i0 + threadIdx.x;
    if (i >= a.nd[d0]) return;
    int node; float acc[K];
    static const int WOFF[4] = {0, 1024, 2560, 4608};
    compute_acc<DEG>(a.x, a.sel[d0], a.nei[d0], ws + WOFF[d0], i, &node, acc);

    const int s = a.sbase[d0] + i;
    inv[node] = (DEG - 1) << 28 | s;
    f32x4* o = (f32x4*)(scored + (size_t)s * K);   // dense 64-B per thread
    o[0] = f32x4{acc[0],  acc[1],  acc[2],  acc[3]};
    o[1] = f32x4{acc[4],  acc[5],  acc[6],  acc[7]};
    o[2] = f32x4{acc[8],  acc[9],  acc[10], acc[11]};
    o[3] = f32x4{acc[12], acc[13], acc[14], acc[15]};
}

__global__ __launch_bounds__(256)
void pass1_kernel(Args a, const float* __restrict__ ws,
                  int* __restrict__ inv, float* __restrict__ scored)
{
    const int bid = blockIdx.x;
    if (bid < a.bcum[0])      pass1_deg<1>(a, ws, inv, scored, 0, bid * 256);
    else if (bid < a.bcum[1]) pass1_deg<2>(a, ws, inv, scored, 1, (bid - a.bcum[0]) * 256);
    else if (bid < a.bcum[2]) pass1_deg<3>(a, ws, inv, scored, 2, (bid - a.bcum[1]) * 256);
    else                      pass1_deg<4>(a, ws, inv, scored, 3, (bid - a.bcum[2]) * 256);
}

__global__ __launch_bounds__(256)
void pass2_kernel(const int* __restrict__ inv, const float* __restrict__ scored,
                  float* __restrict__ out, int n)
{
    const int node = blockIdx.x * 256 + threadIdx.x;
    if (node >= n) return;
    const int v = inv[node];
    const int dm1 = v >> 28;             // 0..3 (top nibble, sign bit clear)
    const int s = v & 0x0FFFFFFF;
    const f32x4* src = (const f32x4*)(scored + (size_t)s * K);
    const f32x4 sc0 = src[0], sc1 = src[1], sc2 = src[2], sc3 = src[3];
    f32x4* o = (f32x4*)(out + (size_t)node * (4 * K));   // dense: wave writes 16 KB contiguous
    const f32x4 z = {0.f, 0.f, 0.f, 0.f};
    #pragma unroll
    for (int b = 0; b < 4; ++b) {
        const bool m = (b == dm1);
        o[b * 4 + 0] = m ? sc0 : z;
        o[b * 4 + 1] = m ? sc1 : z;
        o[b * 4 + 2] = m ? sc2 : z;
        o[b * 4 + 3] = m ? sc3 : z;
    }
}

// ---------------- fallback: direct scatter (round-5 structure) ----------------

template<int DEG>
__device__ __forceinline__ void direct_deg(const Args& a, const float* __restrict__ ws,
                                           float* __restrict__ out, int d0, int i0)
{
    const int i = i0 + threadIdx.x;
    if (i >= a.nd[d0]) return;
    int node; float acc[K];
    static const int WOFF[4] = {0, 1024, 2560, 4608};
    compute_acc<DEG>(a.x, a.sel[d0], a.nei[d0], ws + WOFF[d0], i, &node, acc);

    f32x4* o = (f32x4*)(out + (size_t)node * (4 * K));
    const f32x4 z = {0.f, 0.f, 0.f, 0.f};
    #pragma unroll
    for (int b = 0; b < 4; ++b) {
        if (b == DEG - 1) {
            o[b*4+0] = f32x4{acc[0],  acc[1],  acc[2],  acc[3]};
            o[b*4+1] = f32x4{acc[4],  acc[5],  acc[6],  acc[7]};
            o[b*4+2] = f32x4{acc[8],  acc[9],  acc[10], acc[11]};
            o[b*4+3] = f32x4{acc[12], acc[13], acc[14], acc[15]};
        } else {
            o[b*4+0] = z; o[b*4+1] = z; o[b*4+2] = z; o[b*4+3] = z;
        }
    }
}

__global__ __launch_bounds__(256)
void direct_kernel(Args a, const float* __restrict__ ws, float* __restrict__ out)
{
    const int bid = blockIdx.x;
    if (bid < a.bcum[0])      direct_deg<1>(a, ws, out, 0, bid * 256);
    else if (bid < a.bcum[1]) direct_deg<2>(a, ws, out, 1, (bid - a.bcum[0]) * 256);
    else if (bid < a.bcum[2]) direct_deg<3>(a, ws, out, 2, (bid - a.bcum[1]) * 256);
    else                      direct_deg<4>(a, ws, out, 3, (bid - a.bcum[2]) * 256);
}

extern "C" void kernel_launch(void* const* d_in, const int* in_sizes, int n_in,
                              void* d_out, int out_size, void* d_ws, size_t ws_size,
                              hipStream_t stream)
{
    Args a;
    a.x = (const float*)d_in[0];
    const float* Wf[4]; const float* Wn[4];
    for (int d = 0; d < 4; ++d) {
        a.sel[d] = (const int*)  d_in[1 + 4 * d];
        a.nei[d] = (const int*)  d_in[2 + 4 * d];
        Wf[d]    = (const float*)d_in[3 + 4 * d];
        Wn[d]    = (const float*)d_in[4 + 4 * d];
        a.nd[d]  = in_sizes[1 + 4 * d];
    }
    int cum = 0, scum = 0;
    for (int d = 0; d < 4; ++d) {
        cum += (a.nd[d] + 255) / 256;
        a.bcum[d] = cum;
        a.sbase[d] = scum;
        scum += a.nd[d];
    }
    const int N = scum;

    float* ws  = (float*)d_ws;
    float* out = (float*)d_out;

    prep_w<<<4, 128, 0, stream>>>(Wf[0], Wn[0], Wf[1], Wn[1],
                                  Wf[2], Wn[2], Wf[3], Wn[3], ws);

    const size_t need = ((size_t)WROWS_FLOATS + (size_t)N + (size_t)N * K) * 4;
    if (ws_size >= need) {
        int*   inv    = (int*)(ws + WROWS_FLOATS);
        float* scored = ws + WROWS_FLOATS + N;
        pass1_kernel<<<cum, 256, 0, stream>>>(a, ws, inv, scored);
        pass2_kernel<<<(N + 255) / 256, 256, 0, stream>>>(inv, scored, out, N);
    } else {
        direct_kernel<<<cum, 256, 0, stream>>>(a, ws, out);
    }
}